// Round 1
// baseline (272.950 us; speedup 1.0000x reference)
//
#include <hip/hip_runtime.h>
#include <hip/hip_bf16.h>
#include <cstdint>
#include <cstddef>

#define I_F   1024
#define O_F   1024
#define BATCH 4096
#define KDIM  9216   // 9 * 1024 : j-major (j=0 base/swish, j=1..8 spline bases)
#define EPSC  1e-7f

typedef __bf16 bf16;
typedef __bf16 bf16x8 __attribute__((ext_vector_type(8)));
typedef float  f32x4  __attribute__((ext_vector_type(4)));

// ---------------------------------------------------------------------------
// Kernel 1: activations A[b][j*1024+i] = {swish(x), bases[0..7]}  (bf16)
// ---------------------------------------------------------------------------
__global__ __launch_bounds__(256) void act_kernel(const float* __restrict__ x,
                                                  const float* __restrict__ grid,
                                                  bf16* __restrict__ A) {
    int t = blockIdx.x * 256 + threadIdx.x;      // over 4096*1024, exact
    float xv = x[t];
    int b = t >> 10;
    int i = t & 1023;

    float g[12];
#pragma unroll
    for (int j = 0; j < 12; ++j) g[j] = grid[j];

    float bas[11];
#pragma unroll
    for (int j = 0; j < 11; ++j)
        bas[j] = (xv >= g[j] && xv < g[j + 1]) ? 1.0f : 0.0f;

#pragma unroll
    for (int p = 1; p <= 3; ++p) {
#pragma unroll
        for (int j = 0; j < 11 - 3; ++j) { /* placeholder to keep unroll simple */ }
        // Cox-de Boor step p (in-place forward: bas[j] uses old bas[j], bas[j+1])
#pragma unroll
        for (int j = 0; j < 11; ++j) {
            if (j < 11 - p) {
                float left  = (xv - g[j]) / (g[j + p] - g[j] + EPSC);
                float right = (g[j + p + 1] - xv) / (g[j + p + 1] - g[j + 1] + EPSC);
                bas[j] = left * bas[j] + right * bas[j + 1];
            }
        }
    }

    float sig = 1.0f / (1.0f + __expf(-xv));
    float sw  = xv * sig;

    bf16* out = A + (size_t)b * KDIM + i;
    out[0] = (bf16)sw;
#pragma unroll
    for (int k = 0; k < 8; ++k)
        out[(size_t)(k + 1) * 1024] = (bf16)bas[k];
}

// ---------------------------------------------------------------------------
// Kernel 2: Wt[o][j*1024+i] = { base_scaler[i,o], spline_weight[i,o,k]*spline_scaler[i,o] }
// ---------------------------------------------------------------------------
__global__ __launch_bounds__(256) void wprep_kernel(const float* __restrict__ w,
                                                    const float* __restrict__ ss,
                                                    const float* __restrict__ bs,
                                                    bf16* __restrict__ Wt) {
    int t = blockIdx.x * 256 + threadIdx.x;      // over 1024*1024, exact
    int i = t & 1023;                            // lane-fast over i -> coalesced writes
    int o = t >> 10;
    size_t io = (size_t)i * 1024 + o;
    float scale = ss[io];
    float base  = bs[io];
    const float* wp = w + io * 8;
    f32x4 w0 = *(const f32x4*)(wp);
    f32x4 w1 = *(const f32x4*)(wp + 4);

    bf16* out = Wt + (size_t)o * KDIM + i;
    out[0] = (bf16)base;
#pragma unroll
    for (int k = 0; k < 4; ++k) out[(size_t)(k + 1) * 1024] = (bf16)(w0[k] * scale);
#pragma unroll
    for (int k = 0; k < 4; ++k) out[(size_t)(k + 5) * 1024] = (bf16)(w1[k] * scale);
}

// ---------------------------------------------------------------------------
// Kernel 3: GEMM  out(4096x1024 f32) = A(4096x9216 bf16) * Wt^T(1024x9216 bf16)
// 128x128 tile, BK=64, 4 waves (2x2), mfma_f32_16x16x32_bf16,
// global_load_lds w16 staging, dbuf LDS, T2 XOR swizzle (pre-swizzled source).
// ---------------------------------------------------------------------------
__device__ __forceinline__ void load_lds16(const bf16* g, bf16* l) {
    __builtin_amdgcn_global_load_lds(
        (__attribute__((address_space(1))) void*)g,
        (__attribute__((address_space(3))) void*)l, 16, 0, 0);
}

__global__ __launch_bounds__(256, 1) void gemm_kernel(const bf16* __restrict__ A,
                                                      const bf16* __restrict__ Wt,
                                                      float* __restrict__ C) {
    __shared__ bf16 As[2][128 * 64];   // 2 x 16 KB
    __shared__ bf16 Bs[2][128 * 64];   // 2 x 16 KB

    const int t    = threadIdx.x;
    const int lane = t & 63;
    const int wave = t >> 6;           // 0..3

    // XCD-chunked swizzle: 256 blocks, 8 XCDs -> 32 consecutive per XCD.
    // Decode so each XCD owns one tile_n (Wt panel 2.36MB stays L2-resident).
    int bid = blockIdx.x;
    int swz = (bid & 7) * 32 + (bid >> 3);
    int tm  = swz & 31;                // 32 row tiles
    int tn  = swz >> 5;                // 8 col tiles
    int row0 = tm << 7;
    int col0 = tn << 7;

    // Staging: thread t handles 16B unit u = it*256 + t of each 16KB tile.
    // Physical LDS (linear): row = it*32 + (t>>3), col16_p = t&7.
    // Logical col16 = col16_p ^ (row&7)  -> pre-swizzle the GLOBAL source.
    const int srow = t >> 3;                                  // 0..31
    const int scol = (((t & 7) ^ (srow & 7)) << 3);           // element offset 0..56
    const bf16* gA = A  + (size_t)(row0 + srow) * KDIM + scol;
    const bf16* gB = Wt + (size_t)(col0 + srow) * KDIM + scol;

    const int wm  = wave & 1;          // 2x2 wave grid over 128x128
    const int wn  = wave >> 1;
    const int r15 = lane & 15;
    const int g4  = lane >> 4;
    const int rx  = lane & 7;          // row&7 for frag reads

    f32x4 acc[4][4];
#pragma unroll
    for (int m = 0; m < 4; ++m)
#pragma unroll
        for (int n = 0; n < 4; ++n) acc[m][n] = (f32x4){0.f, 0.f, 0.f, 0.f};

    auto stage = [&](int buf, int kt) {
        const bf16* pa = gA + kt * 64;
        const bf16* pb = gB + kt * 64;
        bf16* la = &As[buf][wave * 512];   // + lane*16B by HW
        bf16* lb = &Bs[buf][wave * 512];
#pragma unroll
        for (int it = 0; it < 4; ++it) {
            load_lds16(pa + it * 32 * KDIM, la + it * 2048);
            load_lds16(pb + it * 32 * KDIM, lb + it * 2048);
        }
    };

    auto compute = [&](int buf) {
#pragma unroll
        for (int kk = 0; kk < 2; ++kk) {
            const int cp = (kk * 4 + g4) ^ rx;    // swizzled 16B-unit col
            bf16x8 af[4], bfr[4];
#pragma unroll
            for (int m = 0; m < 4; ++m) {
                int row = wm * 64 + m * 16 + r15;
                af[m] = *(const bf16x8*)(&As[buf][row * 64 + cp * 8]);
            }
#pragma unroll
            for (int n = 0; n < 4; ++n) {
                int row = wn * 64 + n * 16 + r15;
                bfr[n] = *(const bf16x8*)(&Bs[buf][row * 64 + cp * 8]);
            }
#pragma unroll
            for (int m = 0; m < 4; ++m)
#pragma unroll
                for (int n = 0; n < 4; ++n)
                    acc[m][n] = __builtin_amdgcn_mfma_f32_16x16x32_bf16(
                        af[m], bfr[n], acc[m][n], 0, 0, 0);
        }
    };

    stage(0, 0);
    asm volatile("s_waitcnt vmcnt(0)" ::: "memory");
    __syncthreads();

    int cur = 0;
    const int NT = KDIM / 64;          // 144
    for (int kt = 0; kt < NT - 1; ++kt) {
        stage(cur ^ 1, kt + 1);        // prefetch next tile (in flight over MFMA)
        compute(cur);
        asm volatile("s_waitcnt vmcnt(0)" ::: "memory");
        __syncthreads();
        cur ^= 1;
    }
    compute(cur);

    // Epilogue: C/D layout col=lane&15, row=(lane>>4)*4+reg  [m89]
    float* cptr = C + (size_t)(row0 + wm * 64) * O_F + col0 + wn * 64;
#pragma unroll
    for (int m = 0; m < 4; ++m)
#pragma unroll
        for (int n = 0; n < 4; ++n)
#pragma unroll
            for (int r = 0; r < 4; ++r)
                cptr[(size_t)(m * 16 + g4 * 4 + r) * O_F + n * 16 + r15] = acc[m][n][r];
}

// ---------------------------------------------------------------------------
extern "C" void kernel_launch(void* const* d_in, const int* in_sizes, int n_in,
                              void* d_out, int out_size, void* d_ws, size_t ws_size,
                              hipStream_t stream) {
    const float* x    = (const float*)d_in[0];
    const float* grid = (const float*)d_in[1];
    const float* w    = (const float*)d_in[2];
    const float* ss   = (const float*)d_in[3];
    const float* bs   = (const float*)d_in[4];
    float* out = (float*)d_out;

    bf16* A  = (bf16*)d_ws;                          // 4096*9216*2 = 75.5 MB
    bf16* Wt = A + (size_t)BATCH * KDIM;             // 1024*9216*2 = 18.9 MB

    act_kernel<<<(BATCH * I_F) / 256, 256, 0, stream>>>(x, grid, A);
    wprep_kernel<<<(I_F * O_F) / 256, 256, 0, stream>>>(w, ss, bs, Wt);
    gemm_kernel<<<256, 256, 0, stream>>>(A, Wt, out);
}

// Round 2
// 162.187 us; speedup vs baseline: 1.6829x; 1.6829x over previous
//
#include <hip/hip_runtime.h>
#include <hip/hip_bf16.h>
#include <cstdint>
#include <cstddef>

#define I_F   1024
#define O_F   1024
#define BATCH 4096
#define KDIM  9216   // 9 * 1024 : j-major (j=0 base/swish, j=1..8 spline bases)
#define EPSC  1e-7f

typedef __bf16 bf16;
typedef __bf16 bf16x8 __attribute__((ext_vector_type(8)));
typedef float  f32x4  __attribute__((ext_vector_type(4)));

// ---------------------------------------------------------------------------
// Kernel 1: activations A[b][j*1024+i] = {swish(x), bases[0..7]}  (bf16)
// Divides replaced by v_rcp_f32 of knot-difference reciprocals:
//   left[j]  = (x - g[j]) * r_p[j]
//   right[j] = (g[j+p+1] - x) * r_p[j+1]     (same denominator array shifted)
// ---------------------------------------------------------------------------
__global__ __launch_bounds__(256) void act_kernel(const float* __restrict__ x,
                                                  const float* __restrict__ grid,
                                                  bf16* __restrict__ A) {
    int t = blockIdx.x * 256 + threadIdx.x;      // over 4096*1024, exact
    float xv = x[t];
    int b = t >> 10;
    int i = t & 1023;

    float g[12];
#pragma unroll
    for (int j = 0; j < 12; ++j) g[j] = grid[j];

    float r1[11], r2[10], r3[9];
#pragma unroll
    for (int j = 0; j < 11; ++j) r1[j] = __builtin_amdgcn_rcpf(g[j + 1] - g[j] + EPSC);
#pragma unroll
    for (int j = 0; j < 10; ++j) r2[j] = __builtin_amdgcn_rcpf(g[j + 2] - g[j] + EPSC);
#pragma unroll
    for (int j = 0; j < 9;  ++j) r3[j] = __builtin_amdgcn_rcpf(g[j + 3] - g[j] + EPSC);

    float bas[11];
#pragma unroll
    for (int j = 0; j < 11; ++j)
        bas[j] = (xv >= g[j] && xv < g[j + 1]) ? 1.0f : 0.0f;

    // p = 1
#pragma unroll
    for (int j = 0; j < 10; ++j)
        bas[j] = (xv - g[j]) * r1[j] * bas[j] + (g[j + 2] - xv) * r1[j + 1] * bas[j + 1];
    // p = 2
#pragma unroll
    for (int j = 0; j < 9; ++j)
        bas[j] = (xv - g[j]) * r2[j] * bas[j] + (g[j + 3] - xv) * r2[j + 1] * bas[j + 1];
    // p = 3
#pragma unroll
    for (int j = 0; j < 8; ++j)
        bas[j] = (xv - g[j]) * r3[j] * bas[j] + (g[j + 4] - xv) * r3[j + 1] * bas[j + 1];

    float sig = 1.0f / (1.0f + __expf(-xv));
    float sw  = xv * sig;

    bf16* out = A + (size_t)b * KDIM + i;        // lanes i-fast -> 128B/wave coalesced
    out[0] = (bf16)sw;
#pragma unroll
    for (int k = 0; k < 8; ++k)
        out[(size_t)(k + 1) * 1024] = (bf16)bas[k];
}

// ---------------------------------------------------------------------------
// Kernel 2: Wt[o][j*1024+i] = { base_scaler[i,o], spline_weight[i,o,k]*spline_scaler[i,o] }
// Lanes i-fast (coalesced 128B writes per (o,k)); each thread owns 8 consecutive
// o for one i so the strided w reads are 256B-contiguous per thread (full lines).
// ---------------------------------------------------------------------------
__global__ __launch_bounds__(256) void wprep_kernel(const float* __restrict__ w,
                                                    const float* __restrict__ ss,
                                                    const float* __restrict__ bs,
                                                    bf16* __restrict__ Wt) {
    int g = blockIdx.x * 256 + threadIdx.x;      // 1024 i * 128 o-groups = 131072
    int i  = g & 1023;
    int o0 = (g >> 10) << 3;                     // 8 o per thread
#pragma unroll
    for (int oo = 0; oo < 8; ++oo) {
        int o = o0 + oo;
        size_t io = (size_t)i * 1024 + o;
        float scale = ss[io];
        float base  = bs[io];
        const float* wp = w + io * 8;
        f32x4 w0 = *(const f32x4*)(wp);
        f32x4 w1 = *(const f32x4*)(wp + 4);

        bf16* outp = Wt + (size_t)o * KDIM + i;
        outp[0] = (bf16)base;
#pragma unroll
        for (int k = 0; k < 4; ++k) outp[(size_t)(k + 1) * 1024] = (bf16)(w0[k] * scale);
#pragma unroll
        for (int k = 0; k < 4; ++k) outp[(size_t)(k + 5) * 1024] = (bf16)(w1[k] * scale);
    }
}

// ---------------------------------------------------------------------------
// Kernel 3: GEMM  out(4096x1024 f32) = A(4096x9216 bf16) * Wt^T(1024x9216 bf16)
// 128x128 tile, BK=64, 4 waves (2x2), mfma_f32_16x16x32_bf16,
// global_load_lds w16 staging, dbuf LDS, T2 XOR swizzle (pre-swizzled source).
// Split-K x2: grid 512, blocks 256..511 compute K-half 1 into `dst1`.
// ---------------------------------------------------------------------------
__device__ __forceinline__ void load_lds16(const bf16* g, bf16* l) {
    __builtin_amdgcn_global_load_lds(
        (__attribute__((address_space(1))) void*)g,
        (__attribute__((address_space(3))) void*)l, 16, 0, 0);
}

__global__ __launch_bounds__(256, 1) void gemm_kernel(const bf16* __restrict__ A,
                                                      const bf16* __restrict__ Wt,
                                                      float* __restrict__ dst0,
                                                      float* __restrict__ dst1,
                                                      int ksteps) {
    __shared__ bf16 As[2][128 * 64];   // 2 x 16 KB
    __shared__ bf16 Bs[2][128 * 64];   // 2 x 16 KB

    const int t    = threadIdx.x;
    const int lane = t & 63;
    const int wave = t >> 6;           // 0..3

    const int bid  = blockIdx.x;
    const int half = bid >> 8;         // 0 or 1 (split-K); 0 in fallback grid 256
    const int tb   = bid & 255;
    float* dst = half ? dst1 : dst0;
    const int kbase = half * ksteps;

    // XCD-chunked swizzle over the 256 output tiles
    int swz = (tb & 7) * 32 + (tb >> 3);
    int tm  = swz & 31;                // 32 row tiles
    int tn  = swz >> 5;                // 8 col tiles
    int row0 = tm << 7;
    int col0 = tn << 7;

    // Staging: linear LDS dest (HW: base + lane*16B), pre-swizzled global source.
    const int srow = t >> 3;                                  // 0..31
    const int scol = (((t & 7) ^ (srow & 7)) << 3);           // element offset 0..56
    const bf16* gA = A  + (size_t)(row0 + srow) * KDIM + scol;
    const bf16* gB = Wt + (size_t)(col0 + srow) * KDIM + scol;

    const int wm  = wave & 1;          // 2x2 wave grid over 128x128
    const int wn  = wave >> 1;
    const int r15 = lane & 15;
    const int g4  = lane >> 4;
    const int rx  = lane & 7;          // row&7 for frag reads

    f32x4 acc[4][4];
#pragma unroll
    for (int m = 0; m < 4; ++m)
#pragma unroll
        for (int n = 0; n < 4; ++n) acc[m][n] = (f32x4){0.f, 0.f, 0.f, 0.f};

    auto stage = [&](int buf, int kt) {
        const bf16* pa = gA + kt * 64;
        const bf16* pb = gB + kt * 64;
        bf16* la = &As[buf][wave * 512];   // + lane*16B by HW
        bf16* lb = &Bs[buf][wave * 512];
#pragma unroll
        for (int it = 0; it < 4; ++it) {
            load_lds16(pa + it * 32 * KDIM, la + it * 2048);
            load_lds16(pb + it * 32 * KDIM, lb + it * 2048);
        }
    };

    auto compute = [&](int buf) {
#pragma unroll
        for (int kk = 0; kk < 2; ++kk) {
            const int cp = (kk * 4 + g4) ^ rx;    // swizzled 16B-unit col
            bf16x8 af[4], bfr[4];
#pragma unroll
            for (int m = 0; m < 4; ++m) {
                int row = wm * 64 + m * 16 + r15;
                af[m] = *(const bf16x8*)(&As[buf][row * 64 + cp * 8]);
            }
#pragma unroll
            for (int n = 0; n < 4; ++n) {
                int row = wn * 64 + n * 16 + r15;
                bfr[n] = *(const bf16x8*)(&Bs[buf][row * 64 + cp * 8]);
            }
#pragma unroll
            for (int m = 0; m < 4; ++m)
#pragma unroll
                for (int n = 0; n < 4; ++n)
                    acc[m][n] = __builtin_amdgcn_mfma_f32_16x16x32_bf16(
                        af[m], bfr[n], acc[m][n], 0, 0, 0);
        }
    };

    stage(0, kbase);
    asm volatile("s_waitcnt vmcnt(0)" ::: "memory");
    __syncthreads();

    int cur = 0;
    for (int kt = 0; kt < ksteps - 1; ++kt) {
        stage(cur ^ 1, kbase + kt + 1);   // prefetch next tile (in flight over MFMA)
        compute(cur);
        asm volatile("s_waitcnt vmcnt(0)" ::: "memory");
        __syncthreads();
        cur ^= 1;
    }
    compute(cur);

    // Epilogue: C/D layout col=lane&15, row=(lane>>4)*4+reg  [m89]
    float* cptr = dst + (size_t)(row0 + wm * 64) * O_F + col0 + wn * 64;
#pragma unroll
    for (int m = 0; m < 4; ++m)
#pragma unroll
        for (int n = 0; n < 4; ++n)
#pragma unroll
            for (int r = 0; r < 4; ++r)
                cptr[(size_t)(m * 16 + g4 * 4 + r) * O_F + n * 16 + r15] = acc[m][n][r];
}

// ---------------------------------------------------------------------------
// Kernel 4: out += partial   (split-K reduce), f32x4
// ---------------------------------------------------------------------------
__global__ __launch_bounds__(256) void add_kernel(float* __restrict__ out,
                                                  const float* __restrict__ part) {
    int t = blockIdx.x * 256 + threadIdx.x;      // 1M threads, one f32x4 each
    f32x4 a = *((const f32x4*)out + t);
    f32x4 b = *((const f32x4*)part + t);
    a += b;
    *((f32x4*)out + t) = a;
}

// ---------------------------------------------------------------------------
extern "C" void kernel_launch(void* const* d_in, const int* in_sizes, int n_in,
                              void* d_out, int out_size, void* d_ws, size_t ws_size,
                              hipStream_t stream) {
    const float* x    = (const float*)d_in[0];
    const float* grid = (const float*)d_in[1];
    const float* w    = (const float*)d_in[2];
    const float* ss   = (const float*)d_in[3];
    const float* bs   = (const float*)d_in[4];
    float* out = (float*)d_out;

    const size_t nA = (size_t)BATCH * KDIM * 2;   // 75.5 MB
    const size_t nW = (size_t)O_F   * KDIM * 2;   // 18.9 MB
    const size_t nP = (size_t)BATCH * O_F  * 4;   // 16.8 MB

    bf16* A  = (bf16*)d_ws;
    bf16* Wt = (bf16*)((char*)d_ws + nA);

    act_kernel<<<(BATCH * I_F) / 256, 256, 0, stream>>>(x, grid, A);
    wprep_kernel<<<(I_F * O_F / 8) / 256, 256, 0, stream>>>(w, ss, bs, Wt);

    if (ws_size >= nA + nW + nP) {
        // split-K x2: half 0 -> out, half 1 -> partial, then out += partial
        float* part = (float*)((char*)d_ws + nA + nW);
        gemm_kernel<<<512, 256, 0, stream>>>(A, Wt, out, part, 72);
        add_kernel<<<(BATCH * O_F / 4) / 256, 256, 0, stream>>>(out, part);
    } else {
        gemm_kernel<<<256, 256, 0, stream>>>(A, Wt, out, out, 144);
    }
}

// Round 3
// 155.837 us; speedup vs baseline: 1.7515x; 1.0408x over previous
//
#include <hip/hip_runtime.h>
#include <hip/hip_bf16.h>
#include <cstdint>
#include <cstddef>

#define I_F   1024
#define O_F   1024
#define BATCH 4096
#define KDIM  9216   // 9 * 1024 : j-major (j=0 base/swish, j=1..8 spline bases)
#define EPSC  1e-7f

typedef __bf16 bf16;
typedef __bf16 bf16x4 __attribute__((ext_vector_type(4)));
typedef __bf16 bf16x8 __attribute__((ext_vector_type(8)));
typedef float  f32x4  __attribute__((ext_vector_type(4)));

// ---------------------------------------------------------------------------
// Kernel 1: activations A[b][j*1024+i] = {swish(x), bases[0..7]}  (bf16)
// 4 elements per thread: f32x4 load, 9 x bf16x4 stores (512B/wave per plane).
// Divides replaced by rcp of knot-difference reciprocals (shared tables).
// ---------------------------------------------------------------------------
__global__ __launch_bounds__(256) void act_kernel(const float* __restrict__ x,
                                                  const float* __restrict__ grid,
                                                  bf16* __restrict__ A) {
    int t  = blockIdx.x * 256 + threadIdx.x;     // 1,048,576 threads
    int b  = t >> 8;
    int i0 = (t & 255) << 2;
    f32x4 xv4 = *(const f32x4*)(x + (size_t)b * I_F + i0);

    float g[12];
#pragma unroll
    for (int j = 0; j < 12; ++j) g[j] = grid[j];
    float r1[11], r2[10], r3[9];
#pragma unroll
    for (int j = 0; j < 11; ++j) r1[j] = __builtin_amdgcn_rcpf(g[j + 1] - g[j] + EPSC);
#pragma unroll
    for (int j = 0; j < 10; ++j) r2[j] = __builtin_amdgcn_rcpf(g[j + 2] - g[j] + EPSC);
#pragma unroll
    for (int j = 0; j < 9;  ++j) r3[j] = __builtin_amdgcn_rcpf(g[j + 3] - g[j] + EPSC);

    float sw[4];
    float bs8[4][8];
#pragma unroll
    for (int e = 0; e < 4; ++e) {
        float xv = xv4[e];
        float bas[11];
#pragma unroll
        for (int j = 0; j < 11; ++j)
            bas[j] = (xv >= g[j] && xv < g[j + 1]) ? 1.0f : 0.0f;
#pragma unroll
        for (int j = 0; j < 10; ++j)
            bas[j] = (xv - g[j]) * r1[j] * bas[j] + (g[j + 2] - xv) * r1[j + 1] * bas[j + 1];
#pragma unroll
        for (int j = 0; j < 9; ++j)
            bas[j] = (xv - g[j]) * r2[j] * bas[j] + (g[j + 3] - xv) * r2[j + 1] * bas[j + 1];
#pragma unroll
        for (int j = 0; j < 8; ++j)
            bas[j] = (xv - g[j]) * r3[j] * bas[j] + (g[j + 4] - xv) * r3[j + 1] * bas[j + 1];
#pragma unroll
        for (int k = 0; k < 8; ++k) bs8[e][k] = bas[k];
        float sig = 1.0f / (1.0f + __expf(-xv));
        sw[e] = xv * sig;
    }

    bf16* outp = A + (size_t)b * KDIM + i0;
    *(bf16x4*)(outp) = (bf16x4){(bf16)sw[0], (bf16)sw[1], (bf16)sw[2], (bf16)sw[3]};
#pragma unroll
    for (int k = 0; k < 8; ++k)
        *(bf16x4*)(outp + (size_t)(k + 1) * 1024) =
            (bf16x4){(bf16)bs8[0][k], (bf16)bs8[1][k], (bf16)bs8[2][k], (bf16)bs8[3][k]};
}

// ---------------------------------------------------------------------------
// Kernel 2: Wt[o][j*1024+i] = { base_scaler[i,o], spline_weight[i,o,k]*spline_scaler[i,o] }
// ---------------------------------------------------------------------------
__global__ __launch_bounds__(256) void wprep_kernel(const float* __restrict__ w,
                                                    const float* __restrict__ ss,
                                                    const float* __restrict__ bs,
                                                    bf16* __restrict__ Wt) {
    int g = blockIdx.x * 256 + threadIdx.x;      // 1024 i * 128 o-groups = 131072
    int i  = g & 1023;
    int o0 = (g >> 10) << 3;                     // 8 o per thread
#pragma unroll
    for (int oo = 0; oo < 8; ++oo) {
        int o = o0 + oo;
        size_t io = (size_t)i * 1024 + o;
        float scale = ss[io];
        float base  = bs[io];
        const float* wp = w + io * 8;
        f32x4 w0 = *(const f32x4*)(wp);
        f32x4 w1 = *(const f32x4*)(wp + 4);

        bf16* outp = Wt + (size_t)o * KDIM + i;
        outp[0] = (bf16)base;
#pragma unroll
        for (int k = 0; k < 4; ++k) outp[(size_t)(k + 1) * 1024] = (bf16)(w0[k] * scale);
#pragma unroll
        for (int k = 0; k < 4; ++k) outp[(size_t)(k + 5) * 1024] = (bf16)(w1[k] * scale);
    }
}

// ---------------------------------------------------------------------------
// Kernel 3: GEMM  out = A(4096x9216) * Wt^T(1024x9216), bf16 MFMA.
// 128x128 tile, BK=32, DEPTH-3 counted-vmcnt pipeline (T3+T4), 48KB LDS,
// raw s_barrier, vmcnt(4) in steady state (never 0), T5 setprio around MFMA.
// Frag-read bank swizzle phys = g4 ^ ((r15>>1)&3) via pre-swizzled source.
// ---------------------------------------------------------------------------
__device__ __forceinline__ void load_lds16(const bf16* g, bf16* l) {
    __builtin_amdgcn_global_load_lds(
        (__attribute__((address_space(1))) void*)g,
        (__attribute__((address_space(3))) void*)l, 16, 0, 0);
}

__global__ __launch_bounds__(256, 2) void gemm_kernel(const bf16* __restrict__ A,
                                                      const bf16* __restrict__ Wt,
                                                      float* __restrict__ dst0,
                                                      float* __restrict__ dst1,
                                                      int ksteps) {   // in BK=32 units
    __shared__ __align__(16) bf16 As[3][128 * 32];   // 3 x 8 KB
    __shared__ __align__(16) bf16 Bs[3][128 * 32];   // 3 x 8 KB

    const int t    = threadIdx.x;
    const int lane = t & 63;
    const int wave = t >> 6;           // 0..3

    const int bid  = blockIdx.x;
    const int half = bid >> 8;         // 0/1 split-K; 0 for fallback grid 256
    const int tb   = bid & 255;
    float* dst = half ? dst1 : dst0;
    const size_t kbase = (size_t)half * ksteps * 32;

    // XCD-chunked swizzle over the 256 output tiles (each XCD owns one tn)
    int swz = (tb & 7) * 32 + (tb >> 3);
    int tm  = swz & 31;
    int tn  = swz >> 5;
    int row0 = tm << 7;
    int col0 = tn << 7;

    // Staging: linear LDS dest (HW: base + lane*16B). Thread t, unit u in {t, 256+t}:
    // LDS row = u>>2, phys col16 = t&3. Pre-swizzle global source so that
    // logical col16 stored at phys p is p ^ ((row>>1)&3).
    const int srow = t >> 2;                         // 0..63 (unit1 adds +64 rows)
    const int clog = (t & 3) ^ ((t >> 3) & 3);       // (t>>3)&3 == (srow>>1)&3
    const bf16* gA = A  + (size_t)(row0 + srow) * KDIM + kbase + clog * 8;
    const bf16* gB = Wt + (size_t)(col0 + srow) * KDIM + kbase + clog * 8;

    const int wm  = wave & 1;          // 2x2 wave grid over 128x128
    const int wn  = wave >> 1;
    const int r15 = lane & 15;
    const int g4  = lane >> 4;
    const int cp  = (g4 ^ ((r15 >> 1) & 3)) << 3;    // swizzled element offset

    f32x4 acc[4][4];
#pragma unroll
    for (int m = 0; m < 4; ++m)
#pragma unroll
        for (int n = 0; n < 4; ++n) acc[m][n] = (f32x4){0.f, 0.f, 0.f, 0.f};

    auto stage = [&](int buf, int kt) {
        const bf16* pa = gA + (size_t)kt * 32;
        const bf16* pb = gB + (size_t)kt * 32;
        load_lds16(pa,             &As[buf][wave * 512]);
        load_lds16(pa + 64 * KDIM, &As[buf][2048 + wave * 512]);
        load_lds16(pb,             &Bs[buf][wave * 512]);
        load_lds16(pb + 64 * KDIM, &Bs[buf][2048 + wave * 512]);
    };

    auto compute = [&](int buf) {
        bf16x8 af[4], bfr[4];
#pragma unroll
        for (int m = 0; m < 4; ++m)
            af[m] = *(const bf16x8*)(&As[buf][(wm * 64 + m * 16 + r15) * 32 + cp]);
#pragma unroll
        for (int n = 0; n < 4; ++n)
            bfr[n] = *(const bf16x8*)(&Bs[buf][(wn * 64 + n * 16 + r15) * 32 + cp]);
        __builtin_amdgcn_s_setprio(1);
#pragma unroll
        for (int m = 0; m < 4; ++m)
#pragma unroll
            for (int n = 0; n < 4; ++n)
                acc[m][n] = __builtin_amdgcn_mfma_f32_16x16x32_bf16(
                    af[m], bfr[n], acc[m][n], 0, 0, 0);
        __builtin_amdgcn_s_setprio(0);
    };

    // Prologue: 2 tiles in flight.
    stage(0, 0);
    stage(1, 1);

    int b0 = 0, b2 = 2;
    for (int s = 0; s < ksteps - 2; ++s) {
        asm volatile("s_waitcnt vmcnt(4)" ::: "memory");   // tile s landed; s+1 in flight
        __builtin_amdgcn_s_barrier();
        asm volatile("" ::: "memory");
        stage(b2, s + 2);                                  // issue early (T3 order)
        compute(b0);
        b0 = (b0 == 2) ? 0 : b0 + 1;
        b2 = (b2 == 2) ? 0 : b2 + 1;
    }
    // Tail: two staged tiles remain.
    asm volatile("s_waitcnt vmcnt(4)" ::: "memory");
    __builtin_amdgcn_s_barrier();
    asm volatile("" ::: "memory");
    compute(b0);
    b0 = (b0 == 2) ? 0 : b0 + 1;
    asm volatile("s_waitcnt vmcnt(0)" ::: "memory");
    __builtin_amdgcn_s_barrier();
    asm volatile("" ::: "memory");
    compute(b0);

    // Epilogue: C/D layout col=lane&15, row=(lane>>4)*4+reg  [m89]
    float* cptr = dst + (size_t)(row0 + wm * 64) * O_F + col0 + wn * 64;
#pragma unroll
    for (int m = 0; m < 4; ++m)
#pragma unroll
        for (int n = 0; n < 4; ++n)
#pragma unroll
            for (int r = 0; r < 4; ++r)
                cptr[(size_t)(m * 16 + g4 * 4 + r) * O_F + n * 16 + r15] = acc[m][n][r];
}

// ---------------------------------------------------------------------------
// Kernel 4: out += partial   (split-K reduce), f32x4
// ---------------------------------------------------------------------------
__global__ __launch_bounds__(256) void add_kernel(float* __restrict__ out,
                                                  const float* __restrict__ part) {
    int t = blockIdx.x * 256 + threadIdx.x;
    f32x4 a = *((const f32x4*)out + t);
    f32x4 b = *((const f32x4*)part + t);
    a += b;
    *((f32x4*)out + t) = a;
}

// ---------------------------------------------------------------------------
extern "C" void kernel_launch(void* const* d_in, const int* in_sizes, int n_in,
                              void* d_out, int out_size, void* d_ws, size_t ws_size,
                              hipStream_t stream) {
    const float* x    = (const float*)d_in[0];
    const float* grid = (const float*)d_in[1];
    const float* w    = (const float*)d_in[2];
    const float* ss   = (const float*)d_in[3];
    const float* bs   = (const float*)d_in[4];
    float* out = (float*)d_out;

    const size_t nA = (size_t)BATCH * KDIM * 2;   // 75.5 MB
    const size_t nW = (size_t)O_F   * KDIM * 2;   // 18.9 MB
    const size_t nP = (size_t)BATCH * O_F  * 4;   // 16.8 MB

    bf16* A  = (bf16*)d_ws;
    bf16* Wt = (bf16*)((char*)d_ws + nA);

    act_kernel<<<(BATCH * I_F / 4) / 256, 256, 0, stream>>>(x, grid, A);
    wprep_kernel<<<(I_F * O_F / 8) / 256, 256, 0, stream>>>(w, ss, bs, Wt);

    if (ws_size >= nA + nW + nP) {
        float* part = (float*)((char*)d_ws + nA + nW);
        gemm_kernel<<<512, 256, 0, stream>>>(A, Wt, out, part, 144);   // split-K x2
        add_kernel<<<(BATCH * O_F / 4) / 256, 256, 0, stream>>>(out, part);
    } else {
        gemm_kernel<<<256, 256, 0, stream>>>(A, Wt, out, out, 288);
    }
}